// Round 10
// baseline (743.146 us; speedup 1.0000x reference)
//
#include <hip/hip_runtime.h>
#include <hip/hip_bf16.h>
#include <hip/hip_fp16.h>
#include <cstdint>
#include <cstddef>

#define NB   131072   // items
#define ED   256      // e_dim
#define NQL  4        // levels
#define NEC  256      // codebook entries

typedef _Float16 f16;
typedef f16  f16x8 __attribute__((ext_vector_type(8)));
typedef float f32x4 __attribute__((ext_vector_type(4)));

static constexpr float FMAXV = 3.402823466e+38f;
static constexpr float TAUH  = 0.078125f;   // rescore gate on approx top-2 gap, d/2 units

static constexpr size_t OFF_REC  = (size_t)NB * ED;
static constexpr size_t OFF_LOSS = 2 * (size_t)NB * ED;
static constexpr size_t OFF_SIDX = OFF_LOSS + 1;
static constexpr size_t OFF_RIDX = OFF_SIDX + (size_t)NB * NQL;

// workspace layout (bytes)
static constexpr size_t WS_LOSS = 0;                      // 8 doubles
static constexpr size_t WS_NORM = 256;                    // 8*256 f32 (norm - 256)
static constexpr size_t WS_CBH  = 256 + 8 * 256 * 4;      // 8448; 8*256*256 f16 (1 MB)

// ---- prep: zero loss accumulator + codebook row norms (pre-shifted by -256) ----
__global__ void kPrep(const float* __restrict__ cbS, const float* __restrict__ cbR,
                      float* __restrict__ norms, double* __restrict__ lossAcc) {
  const int cbi = blockIdx.x;    // 0..7
  const int j   = threadIdx.x;   // 0..255
  if (cbi == 0 && j < 8) lossAcc[j] = 0.0;
  const float* row = (cbi < 4 ? cbS : cbR) + ((size_t)(cbi & 3) * NEC + j) * ED;
  float acc = 0.f;
  for (int k = 0; k < ED; k += 4) {
    float4 v = *(const float4*)(row + k);
    acc += v.x * v.x + v.y * v.y + v.z * v.z + v.w * v.w;
  }
  norms[cbi * NEC + j] = acc - 256.0f;   // exact shift (Sterbenz range)
}

// ---- NEGATED f16 copy of codebooks: acc = 0.5*nrm + sum(-c)*r = d/2 ----
__global__ void kConvH(const float* __restrict__ cbS, const float* __restrict__ cbR,
                       f16* __restrict__ cbH) {
  const int f   = blockIdx.x * 256 + threadIdx.x;   // 0..524287
  const int cbi = f >> 16;
  const int rem = f & 65535;
  const float v = (cbi < 4 ? cbS + ((size_t)cbi << 16) : cbR + ((size_t)(cbi - 4) << 16))[rem];
  cbH[f] = (f16)(-v);   // RTN, negated
}

// packed key helpers: low 8 mantissa bits carry the codeword index
__device__ __forceinline__ float pk(float v, int j) {
  return __uint_as_float((__float_as_uint(v) & ~255u) | (unsigned)j);
}
__device__ __forceinline__ float unpv(float k) {
  return __uint_as_float(__float_as_uint(k) & ~255u);
}
__device__ __forceinline__ void ins3(float& s0, float& s1, float& s2, float k) {
  float t0 = fmaxf(s0, k); s0 = fminf(s0, k);
  float t1 = fmaxf(s1, t0); s1 = fminf(s1, t0);
  s2 = fminf(s2, t1);
}
__device__ __forceinline__ void mrg3(float& a0, float& a1, float& a2,
                                     float b0, float b1, float b2) {
  float x  = fmaxf(a0, b0);
  float c0 = fminf(a0, b0);
  float m1 = fminf(a1, b1), M1 = fmaxf(a1, b1);
  float c1 = fminf(fminf(x, a1), b1);
  float c2 = fminf(fminf(fmaxf(x, m1), M1), fminf(a2, b2));
  a0 = c0; a1 = c1; a2 = c2;
}

// ---- 2-level RVQ pass: 32 items/block, res in LDS, independent short blocks ----
// levBase=0: res0 = x-slice -> do lev 0,1 -> write res2 to out's x_q region.
// levBase=2: read res2 -> do lev 2,3 -> write x_q = x - res4 (same region).
// Blocks are chain-free tasks: 4 barriers total; 12 waves/CU (bounds 256,3:
// arch-VGPR cap 84, no res[] in registers -> no spill).
__global__ __launch_bounds__(256, 3)
void kLevPair(const float* __restrict__ x,
              const float* __restrict__ cbS,
              const float* __restrict__ cbR,
              const f16*  __restrict__ cbH,
              const float* __restrict__ norms,
              double* __restrict__ lossAcc,
              float* __restrict__ out,
              int levBase) {
  __shared__ __align__(16) float res[32 * 260];     // fp32 residual tile, padded rows
  __shared__ __align__(16) float4 keybuf[32][4];    // per-wave top-3 per item
  __shared__ float redS[4];

  const int tid  = threadIdx.x;
  const int lane = tid & 63;
  const int w    = tid >> 6;        // wave: owns codewords [64w, 64w+64)
  const int it_o = tid >> 3;        // owner item 0..31 (8 threads/item)
  const int kg   = tid & 7;         // strided k-slot within owner group
  const int l15  = lane & 15;
  const int l4   = lane >> 4;
  const int br   = blockIdx.y;
  const int g0   = blockIdx.x * 32;

  float* resG = out + (br ? OFF_REC : 0);
  const float* cbf32base = br ? cbR : cbS;
  float lossReg = 0.f;

  // ---- load residual tile (linear, fully coalesced: 1KB/instr/wave) ----
  if (levBase == 0) {
#pragma unroll
    for (int k = 0; k < 8; ++k) {
      const int f4 = tid + k * 256;           // float4 index in tile
      const int item = f4 >> 6, kk4 = f4 & 63;
      float4 v = *(const float4*)(x + (size_t)(g0 + item) * (2 * ED) + br * ED + kk4 * 4);
      *(float4*)&res[item * 260 + kk4 * 4] = v;
    }
  } else {
    const float4* src = (const float4*)(resG + (size_t)g0 * ED);
#pragma unroll
    for (int k = 0; k < 8; ++k) {
      const int f4 = tid + k * 256;
      const int item = f4 >> 6, kk4 = f4 & 63;
      *(float4*)&res[item * 260 + kk4 * 4] = src[f4];
    }
  }
  __syncthreads();

#pragma unroll 1
  for (int sub = 0; sub < 2; ++sub) {
    const int lev = levBase + sub;
    const int cbi = br * 4 + lev;
    const float* nrm  = norms + (size_t)cbi * NEC;
    const f16*   cbh  = cbH + ((size_t)cbi << 16);
    const float* cbf32 = cbf32base + (size_t)lev * NEC * ED;

    // ---- acc init = 0.5*nrm (so acc_final = d/2 with negated cbH) ----
    f32x4 acc[2][4];
#pragma unroll
    for (int nt = 0; nt < 4; ++nt) {
      float4 nv = *(const float4*)&nrm[w * 64 + nt * 16 + l4 * 4];
      f32x4 h; h[0] = 0.5f * nv.x; h[1] = 0.5f * nv.y; h[2] = 0.5f * nv.z; h[3] = 0.5f * nv.w;
      acc[0][nt] = h; acc[1][nt] = h;
    }

    // ---- GEMM: 32 items x 64 j per wave, cvt f32->f16 from LDS on the fly ----
#pragma unroll 2
    for (int ks = 0; ks < 8; ++ks) {
      f16x8 A[2];
#pragma unroll
      for (int mt = 0; mt < 2; ++mt) {
        const int base = (mt * 16 + l15) * 260 + ks * 32 + l4 * 8;
        float4 u0 = *(const float4*)&res[base];
        float4 u1 = *(const float4*)&res[base + 4];
        f16x8 h;
        h[0] = (f16)u0.x; h[1] = (f16)u0.y; h[2] = (f16)u0.z; h[3] = (f16)u0.w;
        h[4] = (f16)u1.x; h[5] = (f16)u1.y; h[6] = (f16)u1.z; h[7] = (f16)u1.w;
        A[mt] = h;
      }
      f16x8 Bf[4];
#pragma unroll
      for (int nt = 0; nt < 4; ++nt) {
        const int j = w * 64 + nt * 16 + l15;
        Bf[nt] = *(const f16x8*)&cbh[(size_t)j * ED + ks * 32 + l4 * 8];
      }
#pragma unroll
      for (int mt = 0; mt < 2; ++mt)
#pragma unroll
        for (int nt = 0; nt < 4; ++nt)
          acc[mt][nt] = __builtin_amdgcn_mfma_f32_16x16x32_f16(Bf[nt], A[mt], acc[mt][nt], 0, 0, 0);
    }

    // ---- fold: acc IS d/2; pack index, in-thread + xor16/32 merge ----
#pragma unroll
    for (int mt = 0; mt < 2; ++mt) {
      float s0 = FMAXV, s1 = FMAXV, s2 = FMAXV;
#pragma unroll
      for (int nt = 0; nt < 4; ++nt)
#pragma unroll
        for (int r = 0; r < 4; ++r)
          ins3(s0, s1, s2, pk(acc[mt][nt][r], w * 64 + nt * 16 + l4 * 4 + r));
      {
        float b0k = __shfl_xor(s0, 16), b1k = __shfl_xor(s1, 16), b2k = __shfl_xor(s2, 16);
        mrg3(s0, s1, s2, b0k, b1k, b2k);
        b0k = __shfl_xor(s0, 32); b1k = __shfl_xor(s1, 32); b2k = __shfl_xor(s2, 32);
        mrg3(s0, s1, s2, b0k, b1k, b2k);
      }
      if (l4 == 0) { float4 v; v.x = s0; v.y = s1; v.z = s2; v.w = FMAXV;
                     keybuf[mt * 16 + l15][w] = v; }
    }
    __syncthreads();   // keybuf ready; all GEMM reads of res done

    // ---- merge across waves in the 8-thread owner group ----
    int jm;
    {
      float4 kv = keybuf[it_o][kg & 3];
      float s0 = kv.x, s1 = kv.y, s2 = kv.z;
      float b0k = __shfl_xor(s0, 1), b1k = __shfl_xor(s1, 1), b2k = __shfl_xor(s2, 1);
      mrg3(s0, s1, s2, b0k, b1k, b2k);
      b0k = __shfl_xor(s0, 2); b1k = __shfl_xor(s1, 2); b2k = __shfl_xor(s2, 2);
      mrg3(s0, s1, s2, b0k, b1k, b2k);
      jm = (int)(__float_as_uint(s0) & 255u);
      const float gap = unpv(s1) - unpv(s0);
      if (gap < TAUH) {   // group-uniform: exact fp32 rescore of top-3
        const int cand[3] = { jm, (int)(__float_as_uint(s1) & 255u),
                                  (int)(__float_as_uint(s2) & 255u) };
        float bestd = FMAXV; int bestj = 0;
#pragma unroll 1
        for (int cc = 0; cc < 3; ++cc) {
          const int j = cand[cc];
          const float* row = cbf32 + (size_t)j * ED;
          float p2 = 0.f;
#pragma unroll
          for (int i = 0; i < 8; ++i) {
            const int off = kg * 4 + i * 32;
            float4 q = *(const float4*)&row[off];
            float4 r = *(const float4*)&res[it_o * 260 + off];
            p2 = fmaf(r.x, q.x, p2); p2 = fmaf(r.y, q.y, p2);
            p2 = fmaf(r.z, q.z, p2); p2 = fmaf(r.w, q.w, p2);
          }
          p2 += __shfl_xor(p2, 1);
          p2 += __shfl_xor(p2, 2);
          p2 += __shfl_xor(p2, 4);
          const float d = fmaf(-2.f, p2, nrm[j]);
          if (d < bestd || (d == bestd && j < bestj)) { bestd = d; bestj = j; }
        }
        jm = bestj;
      }
      if (kg == 0) {
        const size_t ioff = (br ? OFF_RIDX : OFF_SIDX) + (size_t)(g0 + it_o) * NQL + lev;
        out[ioff] = (float)jm;
      }
    }

    // ---- residual update + loss (exact reference rounding chain) ----
    {
      const float* crow = cbf32 + (size_t)jm * ED;
      const bool last = (sub == 1);
#pragma unroll
      for (int i = 0; i < 8; ++i) {
        const int off = kg * 4 + i * 32;
        float4 q = *(const float4*)&crow[off];
        float4 r = *(float4*)&res[it_o * 260 + off];
        float4 nr;
#pragma unroll
        for (int u = 0; u < 4; ++u) {
          float cv = (u == 0 ? q.x : u == 1 ? q.y : u == 2 ? q.z : q.w);
          float rv = (u == 0 ? r.x : u == 1 ? r.y : u == 2 ? r.z : r.w);
          float dd = cv - rv;
          lossReg = fmaf(dd, dd, lossReg);
          float xr = rv + dd;            // straight-through x_res
          float rn = rv - xr;
          if (u == 0) nr.x = rn; else if (u == 1) nr.y = rn; else if (u == 2) nr.z = rn; else nr.w = rn;
        }
        if (!last) {
          *(float4*)&res[it_o * 260 + off] = nr;          // LDS for next level
        } else if (levBase == 0) {
          *(float4*)&resG[(size_t)(g0 + it_o) * ED + off] = nr;   // res boundary
        } else {
          float4 xv = *(const float4*)(x + (size_t)(g0 + it_o) * (2 * ED) + br * ED + off);
          float4 o; o.x = xv.x - nr.x; o.y = xv.y - nr.y; o.z = xv.z - nr.z; o.w = xv.w - nr.w;
          *(float4*)&resG[(size_t)(g0 + it_o) * ED + off] = o;    // x_q final
        }
      }
    }
    if (sub == 0) __syncthreads();   // res updated before next level's GEMM
  }

  // ---- loss: one wave-reduce + one atomic per block ----
#pragma unroll
  for (int d = 1; d < 64; d <<= 1) lossReg += __shfl_xor(lossReg, d);
  if (lane == 0) redS[w] = lossReg;
  __syncthreads();
  if (tid == 0)
    atomicAdd(&lossAcc[0], (double)((redS[0] + redS[1]) + (redS[2] + redS[3])));
}

// ---- finalize scalar loss ----
__global__ void kFin(const double* __restrict__ lossAcc, float* __restrict__ out) {
  if (blockIdx.x == 0 && threadIdx.x == 0) {
    out[OFF_LOSS] = (float)(lossAcc[0] * 1.25 / ((double)NB * ED) / 8.0);
  }
}

extern "C" void kernel_launch(void* const* d_in, const int* in_sizes, int n_in,
                              void* d_out, int out_size, void* d_ws, size_t ws_size,
                              hipStream_t stream) {
  const float* x   = (const float*)d_in[0];
  const float* cbS = (const float*)d_in[1];
  const float* cbR = (const float*)d_in[2];
  float* out = (float*)d_out;
  char*  ws  = (char*)d_ws;

  double* lossAcc = (double*)(ws + WS_LOSS);
  float*  norms   = (float*)(ws + WS_NORM);
  f16*    cbH     = (f16*)(ws + WS_CBH);

  hipLaunchKernelGGL(kPrep,  dim3(8),    dim3(256), 0, stream, cbS, cbR, norms, lossAcc);
  hipLaunchKernelGGL(kConvH, dim3(2048), dim3(256), 0, stream, cbS, cbR, cbH);
  hipLaunchKernelGGL(kLevPair, dim3(NB / 32, 2), dim3(256), 0, stream,
                     x, cbS, cbR, cbH, norms, lossAcc, out, 0);
  hipLaunchKernelGGL(kLevPair, dim3(NB / 32, 2), dim3(256), 0, stream,
                     x, cbS, cbR, cbH, norms, lossAcc, out, 2);
  hipLaunchKernelGGL(kFin,   dim3(1),    dim3(64),  0, stream, lossAcc, out);
}